// Round 3
// baseline (392.810 us; speedup 1.0000x reference)
//
#include <hip/hip_runtime.h>
#include <cstdint>
#include <cstddef>

typedef float f32x4 __attribute__((ext_vector_type(4)));

constexpr int BB = 16, CC = 3, HH = 512, WW = 512;
constexpr int HW = HH * WW;
constexpr float RATIO = 0.12f;
constexpr int NB = 1024;            // persistent grid: 4 blocks/CU * 256 CU
constexpr int RPB = 8;              // rows per block (16*512 / 1024)

// ws layout: cnt @0, pmin[1024] @4096, pmax[1024] @8192, imgv @16384

__global__ void initc(unsigned int* cnt) { if (threadIdx.x == 0) *cnt = 0; }

__global__ __launch_bounds__(256, 4) void fused(
        const float* __restrict__ img, float* __restrict__ out,
        unsigned int* __restrict__ cnt, float* __restrict__ pmin,
        float* __restrict__ pmax, float* __restrict__ imgv) {
    int k  = blockIdx.x;
    int t  = threadIdx.x;
    int b  = k >> 6;                 // image (64 blocks per image)
    int r  = k * RPB + (t >> 5);     // global imgv row (0..8191)
    int rr = r & (HH - 1);           // image-local row
    int c0 = (t & 31) << 2;          // col base; chunks at c0 + 128*i

    // ---------- phase A: channel-max + per-block min/max ----------
    const float* ib = img + (size_t)b * CC * HW + (size_t)rr * WW;
    float* vrow = imgv + (size_t)r * WW;
    float mn = 3.4e38f, mx = 0.0f;
    #pragma unroll
    for (int i = 0; i < 4; ++i) {
        int c = c0 + (i << 7);
        f32x4 a0 = *(const f32x4*)(ib + c);
        f32x4 a1 = *(const f32x4*)(ib + HW + c);
        f32x4 a2 = *(const f32x4*)(ib + 2 * HW + c);
        f32x4 v;
        v.x = fmaxf(fmaxf(a0.x, a1.x), a2.x);
        v.y = fmaxf(fmaxf(a0.y, a1.y), a2.y);
        v.z = fmaxf(fmaxf(a0.z, a1.z), a2.z);
        v.w = fmaxf(fmaxf(a0.w, a1.w), a2.w);
        *(f32x4*)(vrow + c) = v;
        mn = fminf(mn, fminf(fminf(v.x, v.y), fminf(v.z, v.w)));
        mx = fmaxf(mx, fmaxf(fmaxf(v.x, v.y), fmaxf(v.z, v.w)));
    }
    #pragma unroll
    for (int s = 32; s > 0; s >>= 1) {
        mn = fminf(mn, __shfl_xor(mn, s, 64));
        mx = fmaxf(mx, __shfl_xor(mx, s, 64));
    }
    __shared__ float smn[4], smx[4];
    int wave = t >> 6;
    if ((t & 63) == 0) { smn[wave] = mn; smx[wave] = mx; }
    __syncthreads();
    if (t == 0) {
        pmin[k] = fminf(fminf(smn[0], smn[1]), fminf(smn[2], smn[3]));
        pmax[k] = fmaxf(fmaxf(smx[0], smx[1]), fmaxf(smx[2], smx[3]));
    }

    // ---------- device-scope barrier (all 1024 blocks co-resident) ----------
    __threadfence();
    if (t == 0) {
        __hip_atomic_fetch_add(cnt, 1u, __ATOMIC_RELEASE, __HIP_MEMORY_SCOPE_AGENT);
        while (__hip_atomic_load(cnt, __ATOMIC_ACQUIRE, __HIP_MEMORY_SCOPE_AGENT) < (unsigned)NB)
            __builtin_amdgcn_s_sleep(2);
    }
    __syncthreads();
    __threadfence();

    // ---------- per-image threshold from 64 partials ----------
    __shared__ float sthr;
    if (t < 64) {
        float m = pmin[(b << 6) + t];
        float M = pmax[(b << 6) + t];
        #pragma unroll
        for (int s = 32; s > 0; s >>= 1) {
            m = fminf(m, __shfl_xor(m, s, 64));
            M = fmaxf(M, __shfl_xor(M, s, 64));
        }
        if (t == 0) sthr = (M - m) * RATIO;
    }
    __syncthreads();
    float thr = sthr;

    // ---------- phase B: 8 neighbor-diff planes x {pos,neg} ----------
    int rm = max(rr - 1, 0), rp = min(rr + 1, HH - 1);
    const float* vb  = imgv + (size_t)b * HW;
    const float* rt_ = vb + (size_t)rm * WW;
    const float* rm_ = vb + (size_t)rr * WW;
    const float* rp_ = vb + (size_t)rp * WW;

    #pragma unroll
    for (int i = 0; i < 4; ++i) {
        int c = c0 + (i << 7);
        int cl = max(c - 1, 0), cr = min(c + 4, WW - 1);
        float vt[6], vm[6], vp[6];
        { f32x4 q = *(const f32x4*)(rt_ + c);
          vt[0] = rt_[cl]; vt[1] = q.x; vt[2] = q.y; vt[3] = q.z; vt[4] = q.w; vt[5] = rt_[cr]; }
        { f32x4 q = *(const f32x4*)(rm_ + c);
          vm[0] = rm_[cl]; vm[1] = q.x; vm[2] = q.y; vm[3] = q.z; vm[4] = q.w; vm[5] = rm_[cr]; }
        { f32x4 q = *(const f32x4*)(rp_ + c);
          vp[0] = rp_[cl]; vp[1] = q.x; vp[2] = q.y; vp[3] = q.z; vp[4] = q.w; vp[5] = rp_[cr]; }

        size_t pixoff = (size_t)rr * WW + c;
        #pragma unroll
        for (int f = 0; f < 8; ++f) {
            float d0, d1, d2, d3;
            switch (f) {   // verified against reference in round 1 (absmax 0.0)
                case 0: d0 = vm[0]-vp[2]; d1 = vm[1]-vp[3]; d2 = vm[2]-vp[4]; d3 = vm[3]-vp[5]; break;
                case 1: d0 = vt[2]-vm[0]; d1 = vt[3]-vm[1]; d2 = vt[4]-vm[2]; d3 = vt[5]-vm[3]; break;
                case 2: d0 = vp[1]-vt[2]; d1 = vp[2]-vt[3]; d2 = vp[3]-vt[4]; d3 = vp[4]-vt[5]; break;
                case 3: d0 = vt[0]-vp[1]; d1 = vt[1]-vp[2]; d2 = vt[2]-vp[3]; d3 = vt[3]-vp[4]; break;
                case 4: d0 = vm[2]-vm[1]; d1 = vm[3]-vm[2]; d2 = vm[4]-vm[3]; d3 = vm[5]-vm[4]; break;
                case 5: d0 = vt[1]-vm[1]; d1 = vt[2]-vm[2]; d2 = vt[3]-vm[3]; d3 = vt[4]-vm[4]; break;
                case 6: d0 = vt[2]-vm[1]; d1 = vt[3]-vm[2]; d2 = vt[4]-vm[3]; d3 = vt[5]-vm[4]; break;
                default:d0 = vt[0]-vm[1]; d1 = vt[1]-vm[2]; d2 = vt[2]-vm[3]; d3 = vt[3]-vm[4]; break;
            }
            f32x4 qp, qn;
            qp.x = (fmaxf(d0, 0.f) >= thr) ? 1.f : 0.f;
            qp.y = (fmaxf(d1, 0.f) >= thr) ? 1.f : 0.f;
            qp.z = (fmaxf(d2, 0.f) >= thr) ? 1.f : 0.f;
            qp.w = (fmaxf(d3, 0.f) >= thr) ? 1.f : 0.f;
            qn.x = (fmaxf(-d0, 0.f) >= thr) ? 1.f : 0.f;
            qn.y = (fmaxf(-d1, 0.f) >= thr) ? 1.f : 0.f;
            qn.z = (fmaxf(-d2, 0.f) >= thr) ? 1.f : 0.f;
            qn.w = (fmaxf(-d3, 0.f) >= thr) ? 1.f : 0.f;
            size_t plane = (size_t)((f * BB + b) * 2);
            *(f32x4*)(out + plane * HW + pixoff)       = qp;
            *(f32x4*)(out + (plane + 1) * HW + pixoff) = qn;
        }
    }
}

extern "C" void kernel_launch(void* const* d_in, const int* in_sizes, int n_in,
                              void* d_out, int out_size, void* d_ws, size_t ws_size,
                              hipStream_t stream) {
    const float* img = (const float*)d_in[0];
    float* out = (float*)d_out;
    unsigned int* cnt = (unsigned int*)d_ws;
    float* pmin = (float*)((char*)d_ws + 4096);
    float* pmax = (float*)((char*)d_ws + 8192);
    float* imgv = (float*)((char*)d_ws + 16384);

    initc<<<1, 64, 0, stream>>>(cnt);
    fused<<<NB, 256, 0, stream>>>(img, out, cnt, pmin, pmax, imgv);
}

// Round 4
// 81.827 us; speedup vs baseline: 4.8005x; 4.8005x over previous
//
#include <hip/hip_runtime.h>
#include <cstdint>
#include <cstddef>

typedef float f32x4 __attribute__((ext_vector_type(4)));

constexpr int BB = 16, CC = 3, HH = 512, WW = 512;
constexpr int HW = HH * WW;
constexpr float RATIO = 0.12f;
constexpr int TR = 16;               // rows per k2 tile
constexpr int TILES = HH / TR;       // 32 tiles per image

// ws layout: pmin[4096] @0, pmax[4096] @16384, imgv @32768.
// No init kernel needed: k1 fully writes pmin/pmax/imgv every call.

__global__ __launch_bounds__(256) void k1_chanmax(
        const float* __restrict__ img, float* __restrict__ pmin,
        float* __restrict__ pmax, float* __restrict__ imgv) {
    int t    = blockIdx.x * 256 + threadIdx.x;
    int off4 = t << 2;                 // 4 pixels per thread
    int b    = off4 / HW;              // uniform per block (256 blocks/image)
    int off  = off4 - b * HW;
    const float* base = img + (size_t)b * CC * HW + off;
    f32x4 c0 = *(const f32x4*)(base);
    f32x4 c1 = *(const f32x4*)(base + HW);
    f32x4 c2 = *(const f32x4*)(base + 2 * HW);
    f32x4 v;
    v.x = fmaxf(fmaxf(c0.x, c1.x), c2.x);
    v.y = fmaxf(fmaxf(c0.y, c1.y), c2.y);
    v.z = fmaxf(fmaxf(c0.z, c1.z), c2.z);
    v.w = fmaxf(fmaxf(c0.w, c1.w), c2.w);
    *(f32x4*)(imgv + (size_t)b * HW + off) = v;

    float mn = fminf(fminf(v.x, v.y), fminf(v.z, v.w));
    float mx = fmaxf(fmaxf(v.x, v.y), fmaxf(v.z, v.w));
    #pragma unroll
    for (int s = 32; s > 0; s >>= 1) {
        mn = fminf(mn, __shfl_xor(mn, s, 64));
        mx = fmaxf(mx, __shfl_xor(mx, s, 64));
    }
    __shared__ float smn[4], smx[4];
    int wave = threadIdx.x >> 6;
    if ((threadIdx.x & 63) == 0) { smn[wave] = mn; smx[wave] = mx; }
    __syncthreads();
    if (threadIdx.x == 0) {
        pmin[blockIdx.x] = fminf(fminf(smn[0], smn[1]), fminf(smn[2], smn[3]));
        pmax[blockIdx.x] = fmaxf(fmaxf(smx[0], smx[1]), fmaxf(smx[2], smx[3]));
    }
}

// One block = one (filter, image, 16-row tile). Writes ONLY its pos/neg plane
// pair -> 2 contiguous 32KB streams per block (DRAM page friendly), vs 16-32
// scattered streams per wave previously.
__global__ __launch_bounds__(256, 4) void k2_edges(
        const float* __restrict__ imgv, const float* __restrict__ pmin,
        const float* __restrict__ pmax, float* __restrict__ out) {
    int bid  = blockIdx.x;
    int tile = bid & (TILES - 1);
    int b    = (bid >> 5) & (BB - 1);
    int f    = bid >> 9;
    int t    = threadIdx.x;

    // ---- per-image threshold from k1's 256 partials (broadcast L2 reads) ----
    __shared__ float sred[8];
    {
        float m = pmin[(b << 8) + t];
        float M = pmax[(b << 8) + t];
        #pragma unroll
        for (int s = 32; s > 0; s >>= 1) {
            m = fminf(m, __shfl_xor(m, s, 64));
            M = fmaxf(M, __shfl_xor(M, s, 64));
        }
        if ((t & 63) == 0) { sred[t >> 6] = m; sred[4 + (t >> 6)] = M; }
    }

    // ---- stage 18 imgv rows (tile rows + halo, row-clamped) into LDS ----
    __shared__ float ld[18 * WW];      // 36864 B
    int tile0 = tile * TR;
    const float* vb = imgv + (size_t)b * HW;
    #pragma unroll
    for (int s = 0; s < 9; ++s) {
        int v  = t + (s << 8);          // vec4 index 0..2303
        int vr = v >> 7;                // lds row 0..17
        int vc = (v & 127) << 2;        // col 0..508
        int g  = min(max(tile0 - 1 + vr, 0), HH - 1);
        *(f32x4*)&ld[vr * WW + vc] = *(const f32x4*)(vb + (size_t)g * WW + vc);
    }
    __syncthreads();
    float thr = (fmaxf(fmaxf(sred[4], sred[5]), fmaxf(sred[6], sred[7]))
               - fminf(fminf(sred[0], sred[1]), fminf(sred[2], sred[3]))) * RATIO;

    // ---- compute + store: 8 iterations of (2 rows x 512 cols) ----
    int c  = (t & 127) << 2;
    int cl = max(c - 1, 0), cr = min(c + 4, WW - 1);
    int rb = t >> 7;                    // 0 or 1
    size_t planep = (size_t)((f * BB + b) * 2) * HW;
    float* outp = out + planep;
    float* outn = out + planep + HW;

    #pragma unroll
    for (int j = 0; j < 8; ++j) {
        int orow = (j << 1) + rb;       // 0..15 within tile
        const float* T = &ld[orow * WW];        // global row rr-1 (clamped)
        const float* M = &ld[(orow + 1) * WW];  // global row rr
        const float* P = &ld[(orow + 2) * WW];  // global row rr+1 (clamped)
        float vt[6], vm[6], vp[6];
        { f32x4 q = *(const f32x4*)(T + c);
          vt[0] = T[cl]; vt[1] = q.x; vt[2] = q.y; vt[3] = q.z; vt[4] = q.w; vt[5] = T[cr]; }
        { f32x4 q = *(const f32x4*)(M + c);
          vm[0] = M[cl]; vm[1] = q.x; vm[2] = q.y; vm[3] = q.z; vm[4] = q.w; vm[5] = M[cr]; }
        { f32x4 q = *(const f32x4*)(P + c);
          vp[0] = P[cl]; vp[1] = q.x; vp[2] = q.y; vp[3] = q.z; vp[4] = q.w; vp[5] = P[cr]; }

        float d0, d1, d2, d3;
        switch (f) {   // formulas verified absmax==0.0 in rounds 1-3
            case 0: d0 = vm[0]-vp[2]; d1 = vm[1]-vp[3]; d2 = vm[2]-vp[4]; d3 = vm[3]-vp[5]; break;
            case 1: d0 = vt[2]-vm[0]; d1 = vt[3]-vm[1]; d2 = vt[4]-vm[2]; d3 = vt[5]-vm[3]; break;
            case 2: d0 = vp[1]-vt[2]; d1 = vp[2]-vt[3]; d2 = vp[3]-vt[4]; d3 = vp[4]-vt[5]; break;
            case 3: d0 = vt[0]-vp[1]; d1 = vt[1]-vp[2]; d2 = vt[2]-vp[3]; d3 = vt[3]-vp[4]; break;
            case 4: d0 = vm[2]-vm[1]; d1 = vm[3]-vm[2]; d2 = vm[4]-vm[3]; d3 = vm[5]-vm[4]; break;
            case 5: d0 = vt[1]-vm[1]; d1 = vt[2]-vm[2]; d2 = vt[3]-vm[3]; d3 = vt[4]-vm[4]; break;
            case 6: d0 = vt[2]-vm[1]; d1 = vt[3]-vm[2]; d2 = vt[4]-vm[3]; d3 = vt[5]-vm[4]; break;
            default:d0 = vt[0]-vm[1]; d1 = vt[1]-vm[2]; d2 = vt[2]-vm[3]; d3 = vt[3]-vm[4]; break;
        }
        f32x4 qp, qn;
        qp.x = (fmaxf(d0, 0.f) >= thr) ? 1.f : 0.f;
        qp.y = (fmaxf(d1, 0.f) >= thr) ? 1.f : 0.f;
        qp.z = (fmaxf(d2, 0.f) >= thr) ? 1.f : 0.f;
        qp.w = (fmaxf(d3, 0.f) >= thr) ? 1.f : 0.f;
        qn.x = (fmaxf(-d0, 0.f) >= thr) ? 1.f : 0.f;
        qn.y = (fmaxf(-d1, 0.f) >= thr) ? 1.f : 0.f;
        qn.z = (fmaxf(-d2, 0.f) >= thr) ? 1.f : 0.f;
        qn.w = (fmaxf(-d3, 0.f) >= thr) ? 1.f : 0.f;

        size_t po = (size_t)(tile0 + orow) * WW + c;
        *(f32x4*)(outp + po) = qp;
        *(f32x4*)(outn + po) = qn;
    }
}

extern "C" void kernel_launch(void* const* d_in, const int* in_sizes, int n_in,
                              void* d_out, int out_size, void* d_ws, size_t ws_size,
                              hipStream_t stream) {
    const float* img = (const float*)d_in[0];
    float* out  = (float*)d_out;
    float* pmin = (float*)d_ws;
    float* pmax = (float*)((char*)d_ws + 16384);
    float* imgv = (float*)((char*)d_ws + 32768);

    k1_chanmax<<<4096, 256, 0, stream>>>(img, pmin, pmax, imgv);
    k2_edges<<<8 * BB * TILES, 256, 0, stream>>>(imgv, pmin, pmax, out);
}

// Round 5
// 74.081 us; speedup vs baseline: 5.3024x; 1.1046x over previous
//
#include <hip/hip_runtime.h>
#include <cstdint>
#include <cstddef>

typedef float f32x4 __attribute__((ext_vector_type(4)));

constexpr int BB = 16, CC = 3, HH = 512, WW = 512;
constexpr int HW = HH * WW;
constexpr float RATIO = 0.12f;
constexpr int TR = 16;               // rows per k2 tile
constexpr int TILES = HH / TR;       // 32 tiles per image

// ws layout: pmin[4096] @0, pmax[4096] @16384, imgv @32768.
// No init kernel needed: k1 fully writes pmin/pmax/imgv every call.

__global__ __launch_bounds__(256) void k1_chanmax(
        const float* __restrict__ img, float* __restrict__ pmin,
        float* __restrict__ pmax, float* __restrict__ imgv) {
    int t    = blockIdx.x * 256 + threadIdx.x;
    int off4 = t << 2;                 // 4 pixels per thread
    int b    = off4 / HW;              // uniform per block (256 blocks/image)
    int off  = off4 - b * HW;
    const float* base = img + (size_t)b * CC * HW + off;
    f32x4 c0 = *(const f32x4*)(base);
    f32x4 c1 = *(const f32x4*)(base + HW);
    f32x4 c2 = *(const f32x4*)(base + 2 * HW);
    f32x4 v;
    v.x = fmaxf(fmaxf(c0.x, c1.x), c2.x);
    v.y = fmaxf(fmaxf(c0.y, c1.y), c2.y);
    v.z = fmaxf(fmaxf(c0.z, c1.z), c2.z);
    v.w = fmaxf(fmaxf(c0.w, c1.w), c2.w);
    *(f32x4*)(imgv + (size_t)b * HW + off) = v;

    float mn = fminf(fminf(v.x, v.y), fminf(v.z, v.w));
    float mx = fmaxf(fmaxf(v.x, v.y), fmaxf(v.z, v.w));
    #pragma unroll
    for (int s = 32; s > 0; s >>= 1) {
        mn = fminf(mn, __shfl_xor(mn, s, 64));
        mx = fmaxf(mx, __shfl_xor(mx, s, 64));
    }
    __shared__ float smn[4], smx[4];
    int wave = threadIdx.x >> 6;
    if ((threadIdx.x & 63) == 0) { smn[wave] = mn; smx[wave] = mx; }
    __syncthreads();
    if (threadIdx.x == 0) {
        pmin[blockIdx.x] = fminf(fminf(smn[0], smn[1]), fminf(smn[2], smn[3]));
        pmax[blockIdx.x] = fmaxf(fmaxf(smx[0], smx[1]), fmaxf(smx[2], smx[3]));
    }
}

// One block = one (filter, image, 16-row tile); writes only its pos/neg plane
// pair (2 contiguous 32KB streams).  blockIdx is swizzled so the 8 filter
// variants of one (image,tile) group land on the SAME XCD (bids congruent
// mod 8, within a 64-bid window): the first block pulls the imgv tile from
// L3, the other 7 hit that XCD's L2 -> ~8x less L3 read demand, which shares
// capacity with the 268MB write stream.
__global__ __launch_bounds__(256, 4) void k2_edges(
        const float* __restrict__ imgv, const float* __restrict__ pmin,
        const float* __restrict__ pmax, float* __restrict__ out) {
    int bid = blockIdx.x;
    int x   = bid & 7;                  // XCD slot
    int m   = bid >> 3;
    int f   = m & 7;                    // filter
    int g   = ((m >> 3) << 3) + x;      // group 0..511 = (image,tile)
    int b    = g >> 5;
    int tile = g & 31;
    int t    = threadIdx.x;

    // ---- per-image threshold from k1's 256 partials (L2-shared within group) ----
    __shared__ float sred[8];
    {
        float mlo = pmin[(b << 8) + t];
        float mhi = pmax[(b << 8) + t];
        #pragma unroll
        for (int s = 32; s > 0; s >>= 1) {
            mlo = fminf(mlo, __shfl_xor(mlo, s, 64));
            mhi = fmaxf(mhi, __shfl_xor(mhi, s, 64));
        }
        if ((t & 63) == 0) { sred[t >> 6] = mlo; sred[4 + (t >> 6)] = mhi; }
    }

    // ---- stage 18 imgv rows (tile rows + halo, row-clamped) into LDS ----
    __shared__ float ld[18 * WW];      // 36864 B
    int tile0 = tile * TR;
    const float* vb = imgv + (size_t)b * HW;
    #pragma unroll
    for (int s = 0; s < 9; ++s) {
        int v  = t + (s << 8);          // vec4 index 0..2303
        int vr = v >> 7;                // lds row 0..17
        int vc = (v & 127) << 2;        // col 0..508
        int g2 = min(max(tile0 - 1 + vr, 0), HH - 1);
        *(f32x4*)&ld[vr * WW + vc] = *(const f32x4*)(vb + (size_t)g2 * WW + vc);
    }
    __syncthreads();
    float thr = (fmaxf(fmaxf(sred[4], sred[5]), fmaxf(sred[6], sred[7]))
               - fminf(fminf(sred[0], sred[1]), fminf(sred[2], sred[3]))) * RATIO;

    // ---- compute + store: 8 iterations of (2 rows x 512 cols) ----
    int c  = (t & 127) << 2;
    int cl = max(c - 1, 0), cr = min(c + 4, WW - 1);
    int rb = t >> 7;                    // 0 or 1
    size_t planep = (size_t)((f * BB + b) * 2) * HW;
    float* outp = out + planep;
    float* outn = out + planep + HW;

    #pragma unroll
    for (int j = 0; j < 8; ++j) {
        int orow = (j << 1) + rb;       // 0..15 within tile
        const float* T = &ld[orow * WW];        // global row rr-1 (clamped)
        const float* M = &ld[(orow + 1) * WW];  // global row rr
        const float* P = &ld[(orow + 2) * WW];  // global row rr+1 (clamped)
        float vt[6], vm[6], vp[6];
        { f32x4 q = *(const f32x4*)(T + c);
          vt[0] = T[cl]; vt[1] = q.x; vt[2] = q.y; vt[3] = q.z; vt[4] = q.w; vt[5] = T[cr]; }
        { f32x4 q = *(const f32x4*)(M + c);
          vm[0] = M[cl]; vm[1] = q.x; vm[2] = q.y; vm[3] = q.z; vm[4] = q.w; vm[5] = M[cr]; }
        { f32x4 q = *(const f32x4*)(P + c);
          vp[0] = P[cl]; vp[1] = q.x; vp[2] = q.y; vp[3] = q.z; vp[4] = q.w; vp[5] = P[cr]; }

        float d0, d1, d2, d3;
        switch (f) {   // formulas verified absmax==0.0 in rounds 1-4
            case 0: d0 = vm[0]-vp[2]; d1 = vm[1]-vp[3]; d2 = vm[2]-vp[4]; d3 = vm[3]-vp[5]; break;
            case 1: d0 = vt[2]-vm[0]; d1 = vt[3]-vm[1]; d2 = vt[4]-vm[2]; d3 = vt[5]-vm[3]; break;
            case 2: d0 = vp[1]-vt[2]; d1 = vp[2]-vt[3]; d2 = vp[3]-vt[4]; d3 = vp[4]-vt[5]; break;
            case 3: d0 = vt[0]-vp[1]; d1 = vt[1]-vp[2]; d2 = vt[2]-vp[3]; d3 = vt[3]-vp[4]; break;
            case 4: d0 = vm[2]-vm[1]; d1 = vm[3]-vm[2]; d2 = vm[4]-vm[3]; d3 = vm[5]-vm[4]; break;
            case 5: d0 = vt[1]-vm[1]; d1 = vt[2]-vm[2]; d2 = vt[3]-vm[3]; d3 = vt[4]-vm[4]; break;
            case 6: d0 = vt[2]-vm[1]; d1 = vt[3]-vm[2]; d2 = vt[4]-vm[3]; d3 = vt[5]-vm[4]; break;
            default:d0 = vt[0]-vm[1]; d1 = vt[1]-vm[2]; d2 = vt[2]-vm[3]; d3 = vt[3]-vm[4]; break;
        }
        f32x4 qp, qn;
        qp.x = (fmaxf(d0, 0.f) >= thr) ? 1.f : 0.f;
        qp.y = (fmaxf(d1, 0.f) >= thr) ? 1.f : 0.f;
        qp.z = (fmaxf(d2, 0.f) >= thr) ? 1.f : 0.f;
        qp.w = (fmaxf(d3, 0.f) >= thr) ? 1.f : 0.f;
        qn.x = (fmaxf(-d0, 0.f) >= thr) ? 1.f : 0.f;
        qn.y = (fmaxf(-d1, 0.f) >= thr) ? 1.f : 0.f;
        qn.z = (fmaxf(-d2, 0.f) >= thr) ? 1.f : 0.f;
        qn.w = (fmaxf(-d3, 0.f) >= thr) ? 1.f : 0.f;

        size_t po = (size_t)(tile0 + orow) * WW + c;
        *(f32x4*)(outp + po) = qp;
        *(f32x4*)(outn + po) = qn;
    }
}

extern "C" void kernel_launch(void* const* d_in, const int* in_sizes, int n_in,
                              void* d_out, int out_size, void* d_ws, size_t ws_size,
                              hipStream_t stream) {
    const float* img = (const float*)d_in[0];
    float* out  = (float*)d_out;
    float* pmin = (float*)d_ws;
    float* pmax = (float*)((char*)d_ws + 16384);
    float* imgv = (float*)((char*)d_ws + 32768);

    k1_chanmax<<<4096, 256, 0, stream>>>(img, pmin, pmax, imgv);
    k2_edges<<<8 * BB * TILES, 256, 0, stream>>>(imgv, pmin, pmax, out);
}

// Round 6
// 65.575 us; speedup vs baseline: 5.9902x; 1.1297x over previous
//
#include <hip/hip_runtime.h>
#include <cstdint>
#include <cstddef>

typedef float f32x4 __attribute__((ext_vector_type(4)));

constexpr int BB = 16, CC = 3, HH = 512, WW = 512;
constexpr int HW = HH * WW;
constexpr float RATIO = 0.12f;
constexpr int TR = 16;               // rows per k2 tile
constexpr int TILES = HH / TR;       // 32 tiles per image

// ws layout: pmin[4096] @0, pmax[4096] @16384.  No imgv: k2 recomputes
// channel-max from img (L3-resident after k1) during LDS staging.

__global__ __launch_bounds__(256) void k1_minmax(
        const float* __restrict__ img, float* __restrict__ pmin,
        float* __restrict__ pmax) {
    int t    = blockIdx.x * 256 + threadIdx.x;
    int off4 = t << 2;                 // 4 pixels per thread
    int b    = off4 / HW;              // uniform per block (256 blocks/image)
    int off  = off4 - b * HW;
    const float* base = img + (size_t)b * CC * HW + off;
    f32x4 c0 = *(const f32x4*)(base);
    f32x4 c1 = *(const f32x4*)(base + HW);
    f32x4 c2 = *(const f32x4*)(base + 2 * HW);
    f32x4 v;
    v.x = fmaxf(fmaxf(c0.x, c1.x), c2.x);
    v.y = fmaxf(fmaxf(c0.y, c1.y), c2.y);
    v.z = fmaxf(fmaxf(c0.z, c1.z), c2.z);
    v.w = fmaxf(fmaxf(c0.w, c1.w), c2.w);

    float mn = fminf(fminf(v.x, v.y), fminf(v.z, v.w));
    float mx = fmaxf(fmaxf(v.x, v.y), fmaxf(v.z, v.w));
    #pragma unroll
    for (int s = 32; s > 0; s >>= 1) {
        mn = fminf(mn, __shfl_xor(mn, s, 64));
        mx = fmaxf(mx, __shfl_xor(mx, s, 64));
    }
    __shared__ float smn[4], smx[4];
    int wave = threadIdx.x >> 6;
    if ((threadIdx.x & 63) == 0) { smn[wave] = mn; smx[wave] = mx; }
    __syncthreads();
    if (threadIdx.x == 0) {
        pmin[blockIdx.x] = fminf(fminf(smn[0], smn[1]), fminf(smn[2], smn[3]));
        pmax[blockIdx.x] = fmaxf(fmaxf(smx[0], smx[1]), fmaxf(smx[2], smx[3]));
    }
}

// One block = one (filter, image, 16-row tile); writes only its pos/neg plane
// pair (2 contiguous 32KB streams).  The 8 filter variants of one (image,tile)
// group land on the SAME XCD (bid mod 8): first member pulls the img tile from
// the clean L3 copy, the other 7 hit that XCD's L2.  Channel-max is recomputed
// during staging (cheap VALU, hidden under the write stream).
__global__ __launch_bounds__(256, 4) void k2_edges(
        const float* __restrict__ img, const float* __restrict__ pmin,
        const float* __restrict__ pmax, float* __restrict__ out) {
    int bid = blockIdx.x;
    int x   = bid & 7;                  // XCD slot
    int m   = bid >> 3;
    int f   = m & 7;                    // filter
    int g   = ((m >> 3) << 3) + x;      // group 0..511 = (image,tile)
    int b    = g >> 5;
    int tile = g & 31;
    int t    = threadIdx.x;

    // ---- per-image threshold from k1's 256 partials ----
    __shared__ float sred[8];
    {
        float mlo = pmin[(b << 8) + t];
        float mhi = pmax[(b << 8) + t];
        #pragma unroll
        for (int s = 32; s > 0; s >>= 1) {
            mlo = fminf(mlo, __shfl_xor(mlo, s, 64));
            mhi = fmaxf(mhi, __shfl_xor(mhi, s, 64));
        }
        if ((t & 63) == 0) { sred[t >> 6] = mlo; sred[4 + (t >> 6)] = mhi; }
    }

    // ---- stage 18 channel-max rows (tile + halo, row-clamped) into LDS ----
    __shared__ float ld[18 * WW];      // 36864 B
    int tile0 = tile * TR;
    const float* ib = img + (size_t)b * CC * HW;
    #pragma unroll
    for (int s = 0; s < 9; ++s) {
        int v  = t + (s << 8);          // vec4 index 0..2303
        int vr = v >> 7;                // lds row 0..17
        int vc = (v & 127) << 2;        // col 0..508
        int g2 = min(max(tile0 - 1 + vr, 0), HH - 1);
        const float* rb = ib + (size_t)g2 * WW + vc;
        f32x4 a0 = *(const f32x4*)(rb);
        f32x4 a1 = *(const f32x4*)(rb + HW);
        f32x4 a2 = *(const f32x4*)(rb + 2 * HW);
        f32x4 q;
        q.x = fmaxf(fmaxf(a0.x, a1.x), a2.x);
        q.y = fmaxf(fmaxf(a0.y, a1.y), a2.y);
        q.z = fmaxf(fmaxf(a0.z, a1.z), a2.z);
        q.w = fmaxf(fmaxf(a0.w, a1.w), a2.w);
        *(f32x4*)&ld[vr * WW + vc] = q;
    }
    __syncthreads();
    float thr = (fmaxf(fmaxf(sred[4], sred[5]), fmaxf(sred[6], sred[7]))
               - fminf(fminf(sred[0], sred[1]), fminf(sred[2], sred[3]))) * RATIO;

    // ---- compute + store: 8 iterations of (2 rows x 512 cols) ----
    int c  = (t & 127) << 2;
    int cl = max(c - 1, 0), cr = min(c + 4, WW - 1);
    int rb2 = t >> 7;                   // 0 or 1
    size_t planep = (size_t)((f * BB + b) * 2) * HW;
    float* outp = out + planep;
    float* outn = out + planep + HW;

    #pragma unroll
    for (int j = 0; j < 8; ++j) {
        int orow = (j << 1) + rb2;      // 0..15 within tile
        const float* T = &ld[orow * WW];        // global row rr-1 (clamped)
        const float* M = &ld[(orow + 1) * WW];  // global row rr
        const float* P = &ld[(orow + 2) * WW];  // global row rr+1 (clamped)
        float vt[6], vm[6], vp[6];
        { f32x4 q = *(const f32x4*)(T + c);
          vt[0] = T[cl]; vt[1] = q.x; vt[2] = q.y; vt[3] = q.z; vt[4] = q.w; vt[5] = T[cr]; }
        { f32x4 q = *(const f32x4*)(M + c);
          vm[0] = M[cl]; vm[1] = q.x; vm[2] = q.y; vm[3] = q.z; vm[4] = q.w; vm[5] = M[cr]; }
        { f32x4 q = *(const f32x4*)(P + c);
          vp[0] = P[cl]; vp[1] = q.x; vp[2] = q.y; vp[3] = q.z; vp[4] = q.w; vp[5] = P[cr]; }

        float d0, d1, d2, d3;
        switch (f) {   // formulas verified absmax==0.0 in rounds 1-5
            case 0: d0 = vm[0]-vp[2]; d1 = vm[1]-vp[3]; d2 = vm[2]-vp[4]; d3 = vm[3]-vp[5]; break;
            case 1: d0 = vt[2]-vm[0]; d1 = vt[3]-vm[1]; d2 = vt[4]-vm[2]; d3 = vt[5]-vm[3]; break;
            case 2: d0 = vp[1]-vt[2]; d1 = vp[2]-vt[3]; d2 = vp[3]-vt[4]; d3 = vp[4]-vt[5]; break;
            case 3: d0 = vt[0]-vp[1]; d1 = vt[1]-vp[2]; d2 = vt[2]-vp[3]; d3 = vt[3]-vp[4]; break;
            case 4: d0 = vm[2]-vm[1]; d1 = vm[3]-vm[2]; d2 = vm[4]-vm[3]; d3 = vm[5]-vm[4]; break;
            case 5: d0 = vt[1]-vm[1]; d1 = vt[2]-vm[2]; d2 = vt[3]-vm[3]; d3 = vt[4]-vm[4]; break;
            case 6: d0 = vt[2]-vm[1]; d1 = vt[3]-vm[2]; d2 = vt[4]-vm[3]; d3 = vt[5]-vm[4]; break;
            default:d0 = vt[0]-vm[1]; d1 = vt[1]-vm[2]; d2 = vt[2]-vm[3]; d3 = vt[3]-vm[4]; break;
        }
        f32x4 qp, qn;
        qp.x = (fmaxf(d0, 0.f) >= thr) ? 1.f : 0.f;
        qp.y = (fmaxf(d1, 0.f) >= thr) ? 1.f : 0.f;
        qp.z = (fmaxf(d2, 0.f) >= thr) ? 1.f : 0.f;
        qp.w = (fmaxf(d3, 0.f) >= thr) ? 1.f : 0.f;
        qn.x = (fmaxf(-d0, 0.f) >= thr) ? 1.f : 0.f;
        qn.y = (fmaxf(-d1, 0.f) >= thr) ? 1.f : 0.f;
        qn.z = (fmaxf(-d2, 0.f) >= thr) ? 1.f : 0.f;
        qn.w = (fmaxf(-d3, 0.f) >= thr) ? 1.f : 0.f;

        size_t po = (size_t)(tile0 + orow) * WW + c;
        *(f32x4*)(outp + po) = qp;
        *(f32x4*)(outn + po) = qn;
    }
}

extern "C" void kernel_launch(void* const* d_in, const int* in_sizes, int n_in,
                              void* d_out, int out_size, void* d_ws, size_t ws_size,
                              hipStream_t stream) {
    const float* img = (const float*)d_in[0];
    float* out  = (float*)d_out;
    float* pmin = (float*)d_ws;
    float* pmax = (float*)((char*)d_ws + 16384);

    k1_minmax<<<4096, 256, 0, stream>>>(img, pmin, pmax);
    k2_edges<<<8 * BB * TILES, 256, 0, stream>>>(img, pmin, pmax, out);
}